// Round 2
// baseline (529.887 us; speedup 1.0000x reference)
//
#include <hip/hip_runtime.h>

#define TT 16   // NUM_TYPES
#define DD 128  // OUT_DIM
#define SCAN_BLK 256
#define SCAN_ITEMS 8
#define SCAN_CHUNK (SCAN_BLK * SCAN_ITEMS)  // 2048

// Kernel A: p = softmax(relu(r@W1+b1) @ Wp + bp), one thread per node.
__global__ __launch_bounds__(256) void k_node_mlp(
    const float* __restrict__ r, const float* __restrict__ W1,
    const float* __restrict__ b1, const float* __restrict__ Wp,
    const float* __restrict__ bp, float* __restrict__ p, int n_nodes)
{
    __shared__ float sW1[TT * DD];   // [16][128]
    __shared__ float sWp[DD * TT];   // [128][16]
    __shared__ float sb1[DD];
    __shared__ float sbp[TT];
    for (int i = threadIdx.x; i < TT * DD; i += 256) { sW1[i] = W1[i]; sWp[i] = Wp[i]; }
    if (threadIdx.x < DD) sb1[threadIdx.x] = b1[threadIdx.x];
    if (threadIdx.x < TT) sbp[threadIdx.x] = bp[threadIdx.x];
    __syncthreads();

    int n = blockIdx.x * 256 + threadIdx.x;
    if (n >= n_nodes) return;

    const float4* rp = (const float4*)(r + (size_t)n * TT);
    float4 r0 = rp[0], r1 = rp[1], r2 = rp[2], r3 = rp[3];
    float rv[TT] = {r0.x, r0.y, r0.z, r0.w, r1.x, r1.y, r1.z, r1.w,
                    r2.x, r2.y, r2.z, r2.w, r3.x, r3.y, r3.z, r3.w};

    float logit[TT];
#pragma unroll
    for (int t = 0; t < TT; ++t) logit[t] = sbp[t];

    for (int j = 0; j < DD; j += 4) {
        float4 z = *(const float4*)(&sb1[j]);
#pragma unroll
        for (int k = 0; k < TT; ++k) {
            float4 w = *(const float4*)(&sW1[k * DD + j]);
            z.x = fmaf(rv[k], w.x, z.x);
            z.y = fmaf(rv[k], w.y, z.y);
            z.z = fmaf(rv[k], w.z, z.z);
            z.w = fmaf(rv[k], w.w, z.w);
        }
        z.x = fmaxf(z.x, 0.f); z.y = fmaxf(z.y, 0.f);
        z.z = fmaxf(z.z, 0.f); z.w = fmaxf(z.w, 0.f);
#pragma unroll
        for (int t4 = 0; t4 < TT; t4 += 4) {
            float4 w0 = *(const float4*)(&sWp[(j + 0) * TT + t4]);
            float4 w1 = *(const float4*)(&sWp[(j + 1) * TT + t4]);
            float4 w2 = *(const float4*)(&sWp[(j + 2) * TT + t4]);
            float4 w3 = *(const float4*)(&sWp[(j + 3) * TT + t4]);
            logit[t4 + 0] += z.x * w0.x + z.y * w1.x + z.z * w2.x + z.w * w3.x;
            logit[t4 + 1] += z.x * w0.y + z.y * w1.y + z.z * w2.y + z.w * w3.y;
            logit[t4 + 2] += z.x * w0.z + z.y * w1.z + z.z * w2.z + z.w * w3.z;
            logit[t4 + 3] += z.x * w0.w + z.y * w1.w + z.z * w2.w + z.w * w3.w;
        }
    }

    float m = logit[0];
#pragma unroll
    for (int t = 1; t < TT; ++t) m = fmaxf(m, logit[t]);
    float e[TT];
    float s = 0.f;
#pragma unroll
    for (int t = 0; t < TT; ++t) { e[t] = expf(logit[t] - m); s += e[t]; }
    float inv = 1.f / s;

    float4* pp = (float4*)(p + (size_t)n * TT);
    pp[0] = make_float4(e[0] * inv, e[1] * inv, e[2] * inv, e[3] * inv);
    pp[1] = make_float4(e[4] * inv, e[5] * inv, e[6] * inv, e[7] * inv);
    pp[2] = make_float4(e[8] * inv, e[9] * inv, e[10] * inv, e[11] * inv);
    pp[3] = make_float4(e[12] * inv, e[13] * inv, e[14] * inv, e[15] * inv);
}

// B1: degree histogram (int atomics, 1 per edge)
__global__ __launch_bounds__(256) void k_hist(
    const int* __restrict__ dst, int* __restrict__ degi, int n_edges)
{
    int e = blockIdx.x * 256 + threadIdx.x;
    if (e < n_edges) atomicAdd(&degi[dst[e]], 1);
}

// B2a: per-chunk sums
__global__ __launch_bounds__(SCAN_BLK) void k_scan1(
    const int* __restrict__ degi, int* __restrict__ bsum, int n)
{
    __shared__ int red[SCAN_BLK];
    int base = blockIdx.x * SCAN_CHUNK + threadIdx.x * SCAN_ITEMS;
    int s = 0;
#pragma unroll
    for (int k = 0; k < SCAN_ITEMS; ++k) { int i = base + k; s += (i < n) ? degi[i] : 0; }
    red[threadIdx.x] = s;
    __syncthreads();
    for (int off = SCAN_BLK / 2; off > 0; off >>= 1) {
        if (threadIdx.x < off) red[threadIdx.x] += red[threadIdx.x + off];
        __syncthreads();
    }
    if (threadIdx.x == 0) bsum[blockIdx.x] = red[0];
}

// B2b: exclusive scan of chunk sums (nb <= 256), single block
__global__ __launch_bounds__(256) void k_scan2(int* __restrict__ bsum, int nb)
{
    __shared__ int tmp[256];
    int t = threadIdx.x;
    tmp[t] = (t < nb) ? bsum[t] : 0;
    __syncthreads();
    if (t == 0) {
        int run = 0;
        for (int b = 0; b < nb; ++b) { int v = tmp[b]; tmp[b] = run; run += v; }
    }
    __syncthreads();
    if (t < nb) bsum[t] = tmp[t];
}

// B2c: full exclusive scan -> offs (and cursor copy)
__global__ __launch_bounds__(SCAN_BLK) void k_scan3(
    const int* __restrict__ degi, const int* __restrict__ bsum,
    int* __restrict__ offs, int* __restrict__ cursor, int n)
{
    __shared__ int ts[SCAN_BLK];
    int t = threadIdx.x;
    int base = blockIdx.x * SCAN_CHUNK + t * SCAN_ITEMS;
    int v[SCAN_ITEMS], loc[SCAN_ITEMS];
    int s = 0;
#pragma unroll
    for (int k = 0; k < SCAN_ITEMS; ++k) {
        int i = base + k;
        v[k] = (i < n) ? degi[i] : 0;
        loc[k] = s;
        s += v[k];
    }
    ts[t] = s;
    __syncthreads();
    for (int off = 1; off < SCAN_BLK; off <<= 1) {
        int x = (t >= off) ? ts[t - off] : 0;
        __syncthreads();
        ts[t] += x;
        __syncthreads();
    }
    int excl = ts[t] - s;                 // exclusive prefix of this thread in block
    int base_off = bsum[blockIdx.x] + excl;
#pragma unroll
    for (int k = 0; k < SCAN_ITEMS; ++k) {
        int i = base + k;
        if (i < n) {
            int o = base_off + loc[k];
            offs[i] = o;
            cursor[i] = o;
            if (i == n - 1) offs[n] = o + v[k];
        }
    }
}

// B3: scatter edges into CSR buckets (src values grouped by dst)
__global__ __launch_bounds__(256) void k_bucket(
    const int* __restrict__ src, const int* __restrict__ dst,
    int* __restrict__ cursor, int* __restrict__ bucket, int n_edges)
{
    int e = blockIdx.x * 256 + threadIdx.x;
    if (e < n_edges) {
        int d = dst[e];
        int pos = atomicAdd(&cursor[d], 1);
        bucket[pos] = src[e];
    }
}

// C: pull-aggregate + mean + final projection + relu.  One wave per node.
// Lane l: edge slot l>>2 (16 edges in flight), float4 chunk l&3 of the p-row.
__global__ __launch_bounds__(256) void k_pull(
    const int* __restrict__ offs, const int* __restrict__ bucket,
    const float* __restrict__ p, const float* __restrict__ Wf,
    const float* __restrict__ bfv, float* __restrict__ out, int n_nodes)
{
    __shared__ float sWf[TT * DD];
    __shared__ float sbf[DD];
    for (int i = threadIdx.x; i < TT * DD; i += 256) sWf[i] = Wf[i];
    if (threadIdx.x < DD) sbf[threadIdx.x] = bfv[threadIdx.x];
    __syncthreads();

    int wave = threadIdx.x >> 6;
    int lane = threadIdx.x & 63;
    int n = blockIdx.x * 4 + wave;
    if (n >= n_nodes) return;

    int beg = offs[n], end = offs[n + 1];
    int sub = lane & 3;
    int slot = lane >> 2;

    float4 acc = make_float4(0.f, 0.f, 0.f, 0.f);
    for (int i = beg + slot; i < end; i += 16) {
        int s = bucket[i];
        float4 v = ((const float4*)(p + (size_t)s * TT))[sub];
        acc.x += v.x; acc.y += v.y; acc.z += v.z; acc.w += v.w;
    }
    // butterfly reduce across the 16 edge slots (lane bits 2..5)
#pragma unroll
    for (int off = 4; off < 64; off <<= 1) {
        acc.x += __shfl_xor(acc.x, off, 64);
        acc.y += __shfl_xor(acc.y, off, 64);
        acc.z += __shfl_xor(acc.z, off, 64);
        acc.w += __shfl_xor(acc.w, off, 64);
    }
    float invd = 1.0f / fmaxf((float)(end - beg), 1.0f);

    // broadcast the 16 mean components to all lanes
    float nd[TT];
#pragma unroll
    for (int t = 0; t < TT; ++t) {
        int g = t >> 2, c = t & 3;
        float x = (c == 0) ? acc.x : (c == 1) ? acc.y : (c == 2) ? acc.z : acc.w;
        nd[t] = __shfl(x, g, 64) * invd;
    }

    // each lane produces 2 consecutive outputs
    int j0 = lane * 2;
    float ox = sbf[j0], oy = sbf[j0 + 1];
#pragma unroll
    for (int t = 0; t < TT; ++t) {
        ox = fmaf(nd[t], sWf[t * DD + j0], ox);
        oy = fmaf(nd[t], sWf[t * DD + j0 + 1], oy);
    }
    ox = fmaxf(ox, 0.f);
    oy = fmaxf(oy, 0.f);
    *(float2*)(out + (size_t)n * DD + j0) = make_float2(ox, oy);
}

extern "C" void kernel_launch(void* const* d_in, const int* in_sizes, int n_in,
                              void* d_out, int out_size, void* d_ws, size_t ws_size,
                              hipStream_t stream) {
    const float* r  = (const float*)d_in[0];
    const int*   src = (const int*)d_in[1];
    const int*   dst = (const int*)d_in[2];
    const float* W1 = (const float*)d_in[3];
    const float* b1 = (const float*)d_in[4];
    const float* Wp = (const float*)d_in[5];
    const float* bp = (const float*)d_in[6];
    const float* Wf = (const float*)d_in[7];
    const float* bf = (const float*)d_in[8];
    float* out = (float*)d_out;

    int n_nodes = in_sizes[0] / TT;
    int n_edges = in_sizes[1];

    // workspace layout (16B-aligned chunks)
    char* ws = (char*)d_ws;
    size_t off = 0;
    float* p      = (float*)(ws + off); off += (size_t)n_nodes * TT * 4;        // 6.4 MB
    int*   bucket = (int*)(ws + off);   off += (size_t)n_edges * 4;             // 12.8 MB
    int*   degi   = (int*)(ws + off);   off += (size_t)n_nodes * 4;
    int*   offs   = (int*)(ws + off);   off += ((size_t)n_nodes + 16) * 4;
    int*   cursor = (int*)(ws + off);   off += (size_t)n_nodes * 4;
    int*   bsum   = (int*)(ws + off);   off += 256 * 4;

    int nb = (n_nodes + SCAN_CHUNK - 1) / SCAN_CHUNK;

    hipMemsetAsync(degi, 0, (size_t)n_nodes * 4, stream);

    int blocksA = (n_nodes + 255) / 256;
    k_node_mlp<<<blocksA, 256, 0, stream>>>(r, W1, b1, Wp, bp, p, n_nodes);

    int blocksE = (n_edges + 255) / 256;
    k_hist<<<blocksE, 256, 0, stream>>>(dst, degi, n_edges);
    k_scan1<<<nb, SCAN_BLK, 0, stream>>>(degi, bsum, n_nodes);
    k_scan2<<<1, 256, 0, stream>>>(bsum, nb);
    k_scan3<<<nb, SCAN_BLK, 0, stream>>>(degi, bsum, offs, cursor, n_nodes);
    k_bucket<<<blocksE, 256, 0, stream>>>(src, dst, cursor, bucket, n_edges);

    int blocksP = (n_nodes + 3) / 4;
    k_pull<<<blocksP, 256, 0, stream>>>(offs, bucket, p, Wf, bf, out, n_nodes);
}

// Round 3
// 450.196 us; speedup vs baseline: 1.1770x; 1.1770x over previous
//
#include <hip/hip_runtime.h>

#define TT 16    // NUM_TYPES
#define DD 128   // OUT_DIM
#define BIN_SHIFT 7          // 128 nodes per bin
#define BIN_NODES 128
#define MAXBINS 800          // >= ceil(100000/128) = 782
#define BIN_CAP 5120         // expected 4096 edges/bin, +16 sigma headroom
#define ITEMS 32             // edges per thread in k_bin (8192 per block)

// Kernel A: p = softmax(relu(r@W1+b1) @ Wp + bp), one thread per node.
__global__ __launch_bounds__(256) void k_node_mlp(
    const float* __restrict__ r, const float* __restrict__ W1,
    const float* __restrict__ b1, const float* __restrict__ Wp,
    const float* __restrict__ bp, float* __restrict__ p, int n_nodes)
{
    __shared__ float sW1[TT * DD];   // [16][128]
    __shared__ float sWp[DD * TT];   // [128][16]
    __shared__ float sb1[DD];
    __shared__ float sbp[TT];
    for (int i = threadIdx.x; i < TT * DD; i += 256) { sW1[i] = W1[i]; sWp[i] = Wp[i]; }
    if (threadIdx.x < DD) sb1[threadIdx.x] = b1[threadIdx.x];
    if (threadIdx.x < TT) sbp[threadIdx.x] = bp[threadIdx.x];
    __syncthreads();

    int n = blockIdx.x * 256 + threadIdx.x;
    if (n >= n_nodes) return;

    const float4* rp = (const float4*)(r + (size_t)n * TT);
    float4 r0 = rp[0], r1 = rp[1], r2 = rp[2], r3 = rp[3];
    float rv[TT] = {r0.x, r0.y, r0.z, r0.w, r1.x, r1.y, r1.z, r1.w,
                    r2.x, r2.y, r2.z, r2.w, r3.x, r3.y, r3.z, r3.w};

    float logit[TT];
#pragma unroll
    for (int t = 0; t < TT; ++t) logit[t] = sbp[t];

    for (int j = 0; j < DD; j += 4) {
        float4 z = *(const float4*)(&sb1[j]);
#pragma unroll
        for (int k = 0; k < TT; ++k) {
            float4 w = *(const float4*)(&sW1[k * DD + j]);
            z.x = fmaf(rv[k], w.x, z.x);
            z.y = fmaf(rv[k], w.y, z.y);
            z.z = fmaf(rv[k], w.z, z.z);
            z.w = fmaf(rv[k], w.w, z.w);
        }
        z.x = fmaxf(z.x, 0.f); z.y = fmaxf(z.y, 0.f);
        z.z = fmaxf(z.z, 0.f); z.w = fmaxf(z.w, 0.f);
#pragma unroll
        for (int t4 = 0; t4 < TT; t4 += 4) {
            float4 w0 = *(const float4*)(&sWp[(j + 0) * TT + t4]);
            float4 w1 = *(const float4*)(&sWp[(j + 1) * TT + t4]);
            float4 w2 = *(const float4*)(&sWp[(j + 2) * TT + t4]);
            float4 w3 = *(const float4*)(&sWp[(j + 3) * TT + t4]);
            logit[t4 + 0] += z.x * w0.x + z.y * w1.x + z.z * w2.x + z.w * w3.x;
            logit[t4 + 1] += z.x * w0.y + z.y * w1.y + z.z * w2.y + z.w * w3.y;
            logit[t4 + 2] += z.x * w0.z + z.y * w1.z + z.z * w2.z + z.w * w3.z;
            logit[t4 + 3] += z.x * w0.w + z.y * w1.w + z.z * w2.w + z.w * w3.w;
        }
    }

    float m = logit[0];
#pragma unroll
    for (int t = 1; t < TT; ++t) m = fmaxf(m, logit[t]);
    float e[TT];
    float s = 0.f;
#pragma unroll
    for (int t = 0; t < TT; ++t) { e[t] = expf(logit[t] - m); s += e[t]; }
    float inv = 1.f / s;

    float4* pp = (float4*)(p + (size_t)n * TT);
    pp[0] = make_float4(e[0] * inv, e[1] * inv, e[2] * inv, e[3] * inv);
    pp[1] = make_float4(e[4] * inv, e[5] * inv, e[6] * inv, e[7] * inv);
    pp[2] = make_float4(e[8] * inv, e[9] * inv, e[10] * inv, e[11] * inv);
    pp[3] = make_float4(e[12] * inv, e[13] * inv, e[14] * inv, e[15] * inv);
}

// k_bin: two-level binning with block-local aggregation.
// Each block stages 256*ITEMS edges, one global atomicAdd per (block,bin),
// then writes packed (src | dst_low<<17) in contiguous runs per bin.
__global__ __launch_bounds__(256) void k_bin(
    const int* __restrict__ src, const int* __restrict__ dst,
    int* __restrict__ binCount, unsigned int* __restrict__ bucket,
    int n_edges, int nbins)
{
    __shared__ int lhist[MAXBINS];
    __shared__ int lbase[MAXBINS];
    for (int i = threadIdx.x; i < nbins; i += 256) lhist[i] = 0;
    __syncthreads();

    int base = blockIdx.x * (256 * ITEMS);
    int myS[ITEMS], myD[ITEMS];
#pragma unroll
    for (int k = 0; k < ITEMS; ++k) {
        int e = base + k * 256 + threadIdx.x;
        if (e < n_edges) { myS[k] = src[e]; myD[k] = dst[e]; }
        else             { myD[k] = -1; }
    }
#pragma unroll
    for (int k = 0; k < ITEMS; ++k)
        if (myD[k] >= 0) atomicAdd(&lhist[myD[k] >> BIN_SHIFT], 1);
    __syncthreads();

    for (int i = threadIdx.x; i < nbins; i += 256) {
        int c = lhist[i];
        lbase[i] = (c > 0) ? atomicAdd(&binCount[i], c) : 0;
        lhist[i] = 0;   // reuse as local cursor
    }
    __syncthreads();

#pragma unroll
    for (int k = 0; k < ITEMS; ++k) {
        if (myD[k] >= 0) {
            int b = myD[k] >> BIN_SHIFT;
            int off = lbase[b] + atomicAdd(&lhist[b], 1);
            if (off < BIN_CAP)
                bucket[(size_t)b * BIN_CAP + off] =
                    (unsigned)myS[k] | ((unsigned)(myD[k] & (BIN_NODES - 1)) << 17);
        }
    }
}

// k_agg: one block per bin.  Accumulate msum/deg for 128 nodes in LDS
// (LDS atomics), then fused mean + final projection + relu, coalesced out.
__global__ __launch_bounds__(256) void k_agg(
    const int* __restrict__ binCount, const unsigned int* __restrict__ bucket,
    const float* __restrict__ p, const float* __restrict__ Wf,
    const float* __restrict__ bfv, float* __restrict__ out, int n_nodes)
{
    __shared__ float sWf[TT * DD];          // 8 KB
    __shared__ float sbf[DD];
    __shared__ float smsum[BIN_NODES][TT];  // 8 KB
    __shared__ int   sdeg[BIN_NODES];

    for (int i = threadIdx.x; i < TT * DD; i += 256) sWf[i] = Wf[i];
    if (threadIdx.x < DD) sbf[threadIdx.x] = bfv[threadIdx.x];
    for (int i = threadIdx.x; i < BIN_NODES * TT; i += 256)
        ((float*)smsum)[i] = 0.f;
    if (threadIdx.x < BIN_NODES) sdeg[threadIdx.x] = 0;
    __syncthreads();

    int b = blockIdx.x;
    int cnt = binCount[b];
    if (cnt > BIN_CAP) cnt = BIN_CAP;
    const unsigned int* bb = bucket + (size_t)b * BIN_CAP;

    int g = threadIdx.x >> 4;   // 16 groups of 16 lanes
    int t = threadIdx.x & 15;
    for (int i = g; i < cnt; i += 16) {
        unsigned pk = bb[i];
        int s  = pk & 0x1FFFF;
        int dl = (pk >> 17) & (BIN_NODES - 1);
        float v = p[(size_t)s * TT + t];   // 16 lanes -> 64B coalesced
        atomicAdd(&smsum[dl][t], v);
        if (t == 0) atomicAdd(&sdeg[dl], 1);
    }
    __syncthreads();

    // 32 lanes per node, 8 nodes per pass, 16 passes
    int node0 = b << BIN_SHIFT;
    int sub = threadIdx.x & 31;
    int j0 = sub * 4;
    for (int nl = threadIdx.x >> 5; nl < BIN_NODES; nl += 8) {
        int n = node0 + nl;
        if (n >= n_nodes) continue;
        float invd = 1.0f / fmaxf((float)sdeg[nl], 1.0f);
        float4 acc = *(const float4*)(&sbf[j0]);
#pragma unroll
        for (int tt = 0; tt < TT; ++tt) {
            float nd = smsum[nl][tt] * invd;
            float4 w = *(const float4*)(&sWf[tt * DD + j0]);
            acc.x = fmaf(nd, w.x, acc.x);
            acc.y = fmaf(nd, w.y, acc.y);
            acc.z = fmaf(nd, w.z, acc.z);
            acc.w = fmaf(nd, w.w, acc.w);
        }
        acc.x = fmaxf(acc.x, 0.f); acc.y = fmaxf(acc.y, 0.f);
        acc.z = fmaxf(acc.z, 0.f); acc.w = fmaxf(acc.w, 0.f);
        *(float4*)(&out[(size_t)n * DD + j0]) = acc;
    }
}

extern "C" void kernel_launch(void* const* d_in, const int* in_sizes, int n_in,
                              void* d_out, int out_size, void* d_ws, size_t ws_size,
                              hipStream_t stream) {
    const float* r   = (const float*)d_in[0];
    const int*   src = (const int*)d_in[1];
    const int*   dst = (const int*)d_in[2];
    const float* W1  = (const float*)d_in[3];
    const float* b1  = (const float*)d_in[4];
    const float* Wp  = (const float*)d_in[5];
    const float* bp  = (const float*)d_in[6];
    const float* Wf  = (const float*)d_in[7];
    const float* bf  = (const float*)d_in[8];
    float* out = (float*)d_out;

    int n_nodes = in_sizes[0] / TT;
    int n_edges = in_sizes[1];
    int nbins = (n_nodes + BIN_NODES - 1) >> BIN_SHIFT;

    char* ws = (char*)d_ws;
    size_t off = 0;
    float* p = (float*)(ws + off);            off += (size_t)n_nodes * TT * 4;   // 6.4 MB
    unsigned int* bucket = (unsigned int*)(ws + off); off += (size_t)nbins * BIN_CAP * 4;  // 16 MB
    int* binCount = (int*)(ws + off);         off += (size_t)nbins * 4;

    hipMemsetAsync(binCount, 0, (size_t)nbins * 4, stream);

    int blocksA = (n_nodes + 255) / 256;
    k_node_mlp<<<blocksA, 256, 0, stream>>>(r, W1, b1, Wp, bp, p, n_nodes);

    int blocksB = (n_edges + 256 * ITEMS - 1) / (256 * ITEMS);
    k_bin<<<blocksB, 256, 0, stream>>>(src, dst, binCount, bucket, n_edges, nbins);

    k_agg<<<nbins, 256, 0, stream>>>(binCount, bucket, p, Wf, bf, out, n_nodes);
}

// Round 4
// 429.296 us; speedup vs baseline: 1.2343x; 1.0487x over previous
//
#include <hip/hip_runtime.h>

#define TT 16    // NUM_TYPES
#define DD 128   // OUT_DIM
#define BIN_SHIFT 7          // 128 nodes per bin
#define BIN_NODES 128
#define MAXBINS 800          // >= ceil(100000/128) = 782
#define BIN_CAP 5120         // expected 4096 edges/bin, +16 sigma headroom
#define ITEMS 32             // edges per thread in k_bin (8192 per block)
#define CHUNK 512            // bucket entries staged in LDS per k_agg pass

__device__ __forceinline__ unsigned short f2bf(float x) {
    unsigned u = __float_as_uint(x);
    u = (u + 0x7FFF + ((u >> 16) & 1)) >> 16;   // round-to-nearest-even
    return (unsigned short)u;
}
__device__ __forceinline__ float bfbits2f(unsigned v) {  // v = bf16 in low 16
    return __uint_as_float(v << 16);
}

// Kernel A: p = softmax(relu(r@W1+b1) @ Wp + bp), one thread per node.
// Output p stored as bf16 (RNE), 32B per row.
__global__ __launch_bounds__(256) void k_node_mlp(
    const float* __restrict__ r, const float* __restrict__ W1,
    const float* __restrict__ b1, const float* __restrict__ Wp,
    const float* __restrict__ bp, unsigned short* __restrict__ pbf, int n_nodes)
{
    __shared__ float sW1[TT * DD];   // [16][128]
    __shared__ float sWp[DD * TT];   // [128][16]
    __shared__ float sb1[DD];
    __shared__ float sbp[TT];
    for (int i = threadIdx.x; i < TT * DD; i += 256) { sW1[i] = W1[i]; sWp[i] = Wp[i]; }
    if (threadIdx.x < DD) sb1[threadIdx.x] = b1[threadIdx.x];
    if (threadIdx.x < TT) sbp[threadIdx.x] = bp[threadIdx.x];
    __syncthreads();

    int n = blockIdx.x * 256 + threadIdx.x;
    if (n >= n_nodes) return;

    const float4* rp = (const float4*)(r + (size_t)n * TT);
    float4 r0 = rp[0], r1 = rp[1], r2 = rp[2], r3 = rp[3];
    float rv[TT] = {r0.x, r0.y, r0.z, r0.w, r1.x, r1.y, r1.z, r1.w,
                    r2.x, r2.y, r2.z, r2.w, r3.x, r3.y, r3.z, r3.w};

    float logit[TT];
#pragma unroll
    for (int t = 0; t < TT; ++t) logit[t] = sbp[t];

    for (int j = 0; j < DD; j += 4) {
        float4 z = *(const float4*)(&sb1[j]);
#pragma unroll
        for (int k = 0; k < TT; ++k) {
            float4 w = *(const float4*)(&sW1[k * DD + j]);
            z.x = fmaf(rv[k], w.x, z.x);
            z.y = fmaf(rv[k], w.y, z.y);
            z.z = fmaf(rv[k], w.z, z.z);
            z.w = fmaf(rv[k], w.w, z.w);
        }
        z.x = fmaxf(z.x, 0.f); z.y = fmaxf(z.y, 0.f);
        z.z = fmaxf(z.z, 0.f); z.w = fmaxf(z.w, 0.f);
#pragma unroll
        for (int t4 = 0; t4 < TT; t4 += 4) {
            float4 w0 = *(const float4*)(&sWp[(j + 0) * TT + t4]);
            float4 w1 = *(const float4*)(&sWp[(j + 1) * TT + t4]);
            float4 w2 = *(const float4*)(&sWp[(j + 2) * TT + t4]);
            float4 w3 = *(const float4*)(&sWp[(j + 3) * TT + t4]);
            logit[t4 + 0] += z.x * w0.x + z.y * w1.x + z.z * w2.x + z.w * w3.x;
            logit[t4 + 1] += z.x * w0.y + z.y * w1.y + z.z * w2.y + z.w * w3.y;
            logit[t4 + 2] += z.x * w0.z + z.y * w1.z + z.z * w2.z + z.w * w3.z;
            logit[t4 + 3] += z.x * w0.w + z.y * w1.w + z.z * w2.w + z.w * w3.w;
        }
    }

    float m = logit[0];
#pragma unroll
    for (int t = 1; t < TT; ++t) m = fmaxf(m, logit[t]);
    float e[TT];
    float s = 0.f;
#pragma unroll
    for (int t = 0; t < TT; ++t) { e[t] = expf(logit[t] - m); s += e[t]; }
    float inv = 1.f / s;

    unsigned h[TT];
#pragma unroll
    for (int t = 0; t < TT; ++t) h[t] = (unsigned)f2bf(e[t] * inv);
    uint4 u0 = make_uint4(h[1] << 16 | h[0],  h[3] << 16 | h[2],
                          h[5] << 16 | h[4],  h[7] << 16 | h[6]);
    uint4 u1 = make_uint4(h[9] << 16 | h[8],  h[11] << 16 | h[10],
                          h[13] << 16 | h[12], h[15] << 16 | h[14]);
    uint4* pp = (uint4*)(pbf + (size_t)n * TT);
    pp[0] = u0;
    pp[1] = u1;
}

// k_bin: two-level binning. One global atomicAdd per (block,bin), packed
// (src | dst_low<<17) entries written in contiguous runs per bin.
__global__ __launch_bounds__(256) void k_bin(
    const int* __restrict__ src, const int* __restrict__ dst,
    int* __restrict__ binCount, unsigned int* __restrict__ bucket,
    int n_edges, int nbins)
{
    __shared__ int lhist[MAXBINS];
    __shared__ int lbase[MAXBINS];
    for (int i = threadIdx.x; i < nbins; i += 256) lhist[i] = 0;
    __syncthreads();

    int base = blockIdx.x * (256 * ITEMS);
    int myS[ITEMS], myD[ITEMS];
#pragma unroll
    for (int k = 0; k < ITEMS; ++k) {
        int e = base + k * 256 + threadIdx.x;
        if (e < n_edges) { myS[k] = src[e]; myD[k] = dst[e]; }
        else             { myD[k] = -1; }
    }
#pragma unroll
    for (int k = 0; k < ITEMS; ++k)
        if (myD[k] >= 0) atomicAdd(&lhist[myD[k] >> BIN_SHIFT], 1);
    __syncthreads();

    for (int i = threadIdx.x; i < nbins; i += 256) {
        int c = lhist[i];
        lbase[i] = (c > 0) ? atomicAdd(&binCount[i], c) : 0;
        lhist[i] = 0;   // reuse as local cursor
    }
    __syncthreads();

#pragma unroll
    for (int k = 0; k < ITEMS; ++k) {
        if (myD[k] >= 0) {
            int b = myD[k] >> BIN_SHIFT;
            int off = lbase[b] + atomicAdd(&lhist[b], 1);
            if (off < BIN_CAP)
                bucket[(size_t)b * BIN_CAP + off] =
                    (unsigned)myS[k] | ((unsigned)(myD[k] & (BIN_NODES - 1)) << 17);
        }
    }
}

// k_agg: nsplit blocks per bin. LDS-staged bucket chunks, 8-lane groups,
// unroll-4 independent bf16 gathers, LDS atomic accumulate, partial write-out.
__global__ __launch_bounds__(256) void k_agg(
    const int* __restrict__ binCount, const unsigned int* __restrict__ bucket,
    const unsigned short* __restrict__ pbf,
    float* __restrict__ msum_part, float* __restrict__ deg_part,
    int n_nodes, int nsplit)
{
    __shared__ unsigned chunk[CHUNK];          // 2 KB
    __shared__ float smsum[BIN_NODES][TT];     // 8 KB
    __shared__ int   sdeg[BIN_NODES];

    for (int i = threadIdx.x; i < BIN_NODES * TT; i += 256)
        ((float*)smsum)[i] = 0.f;
    if (threadIdx.x < BIN_NODES) sdeg[threadIdx.x] = 0;
    __syncthreads();

    int b    = blockIdx.x / nsplit;
    int part = blockIdx.x % nsplit;
    int cnt = binCount[b];
    if (cnt > BIN_CAP) cnt = BIN_CAP;
    int per = (cnt + nsplit - 1) / nsplit;
    int beg = part * per;
    int end = min(cnt, beg + per);
    const unsigned* bb = bucket + (size_t)b * BIN_CAP;
    const unsigned* prow = (const unsigned*)pbf;   // 8 uints per node row

    int g = threadIdx.x >> 3;   // 32 groups of 8 lanes
    int j = threadIdx.x & 7;

    for (int c0 = beg; c0 < end; c0 += CHUNK) {
        int m = min(CHUNK, end - c0);
        __syncthreads();   // protect chunk[] reuse
        for (int i = threadIdx.x; i < m; i += 256) chunk[i] = bb[c0 + i];
        __syncthreads();

        if (m == CHUNK) {
#pragma unroll
            for (int k0 = 0; k0 < 16; k0 += 4) {
                unsigned pk0 = chunk[g + (k0 + 0) * 32];
                unsigned pk1 = chunk[g + (k0 + 1) * 32];
                unsigned pk2 = chunk[g + (k0 + 2) * 32];
                unsigned pk3 = chunk[g + (k0 + 3) * 32];
                unsigned v0 = prow[(size_t)(pk0 & 0x1FFFF) * 8 + j];
                unsigned v1 = prow[(size_t)(pk1 & 0x1FFFF) * 8 + j];
                unsigned v2 = prow[(size_t)(pk2 & 0x1FFFF) * 8 + j];
                unsigned v3 = prow[(size_t)(pk3 & 0x1FFFF) * 8 + j];
                int d0 = (pk0 >> 17) & 127, d1 = (pk1 >> 17) & 127;
                int d2 = (pk2 >> 17) & 127, d3 = (pk3 >> 17) & 127;
                atomicAdd(&smsum[d0][2 * j],     bfbits2f(v0 & 0xFFFF));
                atomicAdd(&smsum[d0][2 * j + 1], bfbits2f(v0 >> 16));
                atomicAdd(&smsum[d1][2 * j],     bfbits2f(v1 & 0xFFFF));
                atomicAdd(&smsum[d1][2 * j + 1], bfbits2f(v1 >> 16));
                atomicAdd(&smsum[d2][2 * j],     bfbits2f(v2 & 0xFFFF));
                atomicAdd(&smsum[d2][2 * j + 1], bfbits2f(v2 >> 16));
                atomicAdd(&smsum[d3][2 * j],     bfbits2f(v3 & 0xFFFF));
                atomicAdd(&smsum[d3][2 * j + 1], bfbits2f(v3 >> 16));
                if (j == 0) {
                    atomicAdd(&sdeg[d0], 1); atomicAdd(&sdeg[d1], 1);
                    atomicAdd(&sdeg[d2], 1); atomicAdd(&sdeg[d3], 1);
                }
            }
        } else {
            for (int i = g; i < m; i += 32) {
                unsigned pk = chunk[i];
                unsigned v = prow[(size_t)(pk & 0x1FFFF) * 8 + j];
                int dl = (pk >> 17) & 127;
                atomicAdd(&smsum[dl][2 * j],     bfbits2f(v & 0xFFFF));
                atomicAdd(&smsum[dl][2 * j + 1], bfbits2f(v >> 16));
                if (j == 0) atomicAdd(&sdeg[dl], 1);
            }
        }
    }
    __syncthreads();

    int node0 = b << BIN_SHIFT;
    int valid = min(BIN_NODES, n_nodes - node0);
    if (valid > 0) {
        float* mp = msum_part + (size_t)part * n_nodes * TT + (size_t)node0 * TT;
        for (int i = threadIdx.x; i < valid * 4; i += 256)
            ((float4*)mp)[i] = ((const float4*)smsum)[i];
        float* dp = deg_part + (size_t)part * n_nodes + node0;
        if (threadIdx.x < valid) dp[threadIdx.x] = (float)sdeg[threadIdx.x];
    }
}

// k_final: sum partials, mean, 16->128 projection, relu. 32 threads/node.
__global__ __launch_bounds__(256) void k_final(
    const float* __restrict__ msum_part, const float* __restrict__ deg_part,
    const float* __restrict__ Wf, const float* __restrict__ bfv,
    float* __restrict__ out, int n_nodes, int nsplit)
{
    __shared__ float sWf[TT * DD];
    __shared__ float sbf[DD];
    for (int i = threadIdx.x; i < TT * DD; i += 256) sWf[i] = Wf[i];
    if (threadIdx.x < DD) sbf[threadIdx.x] = bfv[threadIdx.x];
    __syncthreads();

    long long gid = (long long)blockIdx.x * 256 + threadIdx.x;
    int n = (int)(gid >> 5);
    int j0 = (int)(gid & 31) * 4;
    if (n >= n_nodes) return;

    float degv = 0.f;
    for (int s = 0; s < nsplit; ++s) degv += deg_part[(size_t)s * n_nodes + n];
    float invd = 1.0f / fmaxf(degv, 1.0f);

    float4 acc = *(const float4*)(&sbf[j0]);
#pragma unroll
    for (int t = 0; t < TT; ++t) {
        float nd = 0.f;
        for (int s = 0; s < nsplit; ++s)
            nd += msum_part[((size_t)s * n_nodes + n) * TT + t];
        nd *= invd;
        float4 w = *(const float4*)(&sWf[t * DD + j0]);
        acc.x = fmaf(nd, w.x, acc.x);
        acc.y = fmaf(nd, w.y, acc.y);
        acc.z = fmaf(nd, w.z, acc.z);
        acc.w = fmaf(nd, w.w, acc.w);
    }
    acc.x = fmaxf(acc.x, 0.f); acc.y = fmaxf(acc.y, 0.f);
    acc.z = fmaxf(acc.z, 0.f); acc.w = fmaxf(acc.w, 0.f);
    *(float4*)(&out[(size_t)n * DD + j0]) = acc;
}

extern "C" void kernel_launch(void* const* d_in, const int* in_sizes, int n_in,
                              void* d_out, int out_size, void* d_ws, size_t ws_size,
                              hipStream_t stream) {
    const float* r   = (const float*)d_in[0];
    const int*   src = (const int*)d_in[1];
    const int*   dst = (const int*)d_in[2];
    const float* W1  = (const float*)d_in[3];
    const float* b1  = (const float*)d_in[4];
    const float* Wp  = (const float*)d_in[5];
    const float* bp  = (const float*)d_in[6];
    const float* Wf  = (const float*)d_in[7];
    const float* bf  = (const float*)d_in[8];
    float* out = (float*)d_out;

    int n_nodes = in_sizes[0] / TT;
    int n_edges = in_sizes[1];
    int nbins = (n_nodes + BIN_NODES - 1) >> BIN_SHIFT;

    auto al = [](size_t x) { return (x + 255) & ~(size_t)255; };
    size_t pB  = al((size_t)n_nodes * TT * 2);
    size_t bkB = al((size_t)nbins * BIN_CAP * 4);
    size_t bcB = al((size_t)nbins * 4);
    // pick split factor that fits the workspace
    int nsplit = 2;
    {
        size_t mpB = al((size_t)nsplit * n_nodes * TT * 4);
        size_t dpB = al((size_t)nsplit * n_nodes * 4);
        if (pB + bkB + bcB + mpB + dpB > ws_size) nsplit = 1;
    }
    size_t mpB = al((size_t)nsplit * n_nodes * TT * 4);

    char* ws = (char*)d_ws;
    size_t off = 0;
    unsigned short* pbf = (unsigned short*)(ws + off); off += pB;
    unsigned int* bucket = (unsigned int*)(ws + off);  off += bkB;
    int* binCount = (int*)(ws + off);                  off += bcB;
    float* msum_part = (float*)(ws + off);             off += mpB;
    float* deg_part = (float*)(ws + off);

    hipMemsetAsync(binCount, 0, (size_t)nbins * 4, stream);

    int blocksA = (n_nodes + 255) / 256;
    k_node_mlp<<<blocksA, 256, 0, stream>>>(r, W1, b1, Wp, bp, pbf, n_nodes);

    int blocksB = (n_edges + 256 * ITEMS - 1) / (256 * ITEMS);
    k_bin<<<blocksB, 256, 0, stream>>>(src, dst, binCount, bucket, n_edges, nbins);

    k_agg<<<nbins * nsplit, 256, 0, stream>>>(binCount, bucket, pbf,
                                              msum_part, deg_part, n_nodes, nsplit);

    int blocksF = (int)(((long long)n_nodes * 32 + 255) / 256);
    k_final<<<blocksF, 256, 0, stream>>>(msum_part, deg_part, Wf, bf, out,
                                         n_nodes, nsplit);
}

// Round 5
// 111.461 us; speedup vs baseline: 4.7540x; 3.8515x over previous
//
#include <hip/hip_runtime.h>

#define TT 16    // NUM_TYPES
#define DD 128   // OUT_DIM
#define BIN_SHIFT 7          // 128 nodes per bin
#define BIN_NODES 128
#define MAXBINS 800          // >= ceil(100000/128) = 782
#define BIN_CAP 5120         // expected 4096 edges/bin, +16 sigma headroom
#define ITEMS 32             // edges per thread in k_bin (8192 per block)

__device__ __forceinline__ unsigned short f2bf(float x) {
    unsigned u = __float_as_uint(x);
    u = (u + 0x7FFF + ((u >> 16) & 1)) >> 16;   // round-to-nearest-even
    return (unsigned short)u;
}
__device__ __forceinline__ float bfbits2f(unsigned v) {  // v = bf16 in low 16
    return __uint_as_float(v << 16);
}

// Kernel A: p = softmax(relu(r@W1+b1) @ Wp + bp), one thread per node.
// Output p stored as bf16 (RNE), 32B per row.
__global__ __launch_bounds__(256) void k_node_mlp(
    const float* __restrict__ r, const float* __restrict__ W1,
    const float* __restrict__ b1, const float* __restrict__ Wp,
    const float* __restrict__ bp, unsigned short* __restrict__ pbf, int n_nodes)
{
    __shared__ float sW1[TT * DD];   // [16][128]
    __shared__ float sWp[DD * TT];   // [128][16]
    __shared__ float sb1[DD];
    __shared__ float sbp[TT];
    for (int i = threadIdx.x; i < TT * DD; i += 256) { sW1[i] = W1[i]; sWp[i] = Wp[i]; }
    if (threadIdx.x < DD) sb1[threadIdx.x] = b1[threadIdx.x];
    if (threadIdx.x < TT) sbp[threadIdx.x] = bp[threadIdx.x];
    __syncthreads();

    int n = blockIdx.x * 256 + threadIdx.x;
    if (n >= n_nodes) return;

    const float4* rp = (const float4*)(r + (size_t)n * TT);
    float4 r0 = rp[0], r1 = rp[1], r2 = rp[2], r3 = rp[3];
    float rv[TT] = {r0.x, r0.y, r0.z, r0.w, r1.x, r1.y, r1.z, r1.w,
                    r2.x, r2.y, r2.z, r2.w, r3.x, r3.y, r3.z, r3.w};

    float logit[TT];
#pragma unroll
    for (int t = 0; t < TT; ++t) logit[t] = sbp[t];

    for (int j = 0; j < DD; j += 4) {
        float4 z = *(const float4*)(&sb1[j]);
#pragma unroll
        for (int k = 0; k < TT; ++k) {
            float4 w = *(const float4*)(&sW1[k * DD + j]);
            z.x = fmaf(rv[k], w.x, z.x);
            z.y = fmaf(rv[k], w.y, z.y);
            z.z = fmaf(rv[k], w.z, z.z);
            z.w = fmaf(rv[k], w.w, z.w);
        }
        z.x = fmaxf(z.x, 0.f); z.y = fmaxf(z.y, 0.f);
        z.z = fmaxf(z.z, 0.f); z.w = fmaxf(z.w, 0.f);
#pragma unroll
        for (int t4 = 0; t4 < TT; t4 += 4) {
            float4 w0 = *(const float4*)(&sWp[(j + 0) * TT + t4]);
            float4 w1 = *(const float4*)(&sWp[(j + 1) * TT + t4]);
            float4 w2 = *(const float4*)(&sWp[(j + 2) * TT + t4]);
            float4 w3 = *(const float4*)(&sWp[(j + 3) * TT + t4]);
            logit[t4 + 0] += z.x * w0.x + z.y * w1.x + z.z * w2.x + z.w * w3.x;
            logit[t4 + 1] += z.x * w0.y + z.y * w1.y + z.z * w2.y + z.w * w3.y;
            logit[t4 + 2] += z.x * w0.z + z.y * w1.z + z.z * w2.z + z.w * w3.z;
            logit[t4 + 3] += z.x * w0.w + z.y * w1.w + z.z * w2.w + z.w * w3.w;
        }
    }

    float m = logit[0];
#pragma unroll
    for (int t = 1; t < TT; ++t) m = fmaxf(m, logit[t]);
    float e[TT];
    float s = 0.f;
#pragma unroll
    for (int t = 0; t < TT; ++t) { e[t] = expf(logit[t] - m); s += e[t]; }
    float inv = 1.f / s;

    unsigned h[TT];
#pragma unroll
    for (int t = 0; t < TT; ++t) h[t] = (unsigned)f2bf(e[t] * inv);
    uint4 u0 = make_uint4(h[1] << 16 | h[0],  h[3] << 16 | h[2],
                          h[5] << 16 | h[4],  h[7] << 16 | h[6]);
    uint4 u1 = make_uint4(h[9] << 16 | h[8],  h[11] << 16 | h[10],
                          h[13] << 16 | h[12], h[15] << 16 | h[14]);
    uint4* pp = (uint4*)(pbf + (size_t)n * TT);
    pp[0] = u0;
    pp[1] = u1;
}

// k_bin: two-level binning. One global atomicAdd per (block,bin), packed
// (src | dst_low<<17) entries written in contiguous runs per bin.
__global__ __launch_bounds__(256) void k_bin(
    const int* __restrict__ src, const int* __restrict__ dst,
    int* __restrict__ binCount, unsigned int* __restrict__ bucket,
    int n_edges, int nbins)
{
    __shared__ int lhist[MAXBINS];
    __shared__ int lbase[MAXBINS];
    for (int i = threadIdx.x; i < nbins; i += 256) lhist[i] = 0;
    __syncthreads();

    int base = blockIdx.x * (256 * ITEMS);
    int myS[ITEMS], myD[ITEMS];
#pragma unroll
    for (int k = 0; k < ITEMS; ++k) {
        int e = base + k * 256 + threadIdx.x;
        if (e < n_edges) { myS[k] = src[e]; myD[k] = dst[e]; }
        else             { myD[k] = -1; }
    }
#pragma unroll
    for (int k = 0; k < ITEMS; ++k)
        if (myD[k] >= 0) atomicAdd(&lhist[myD[k] >> BIN_SHIFT], 1);
    __syncthreads();

    for (int i = threadIdx.x; i < nbins; i += 256) {
        int c = lhist[i];
        lbase[i] = (c > 0) ? atomicAdd(&binCount[i], c) : 0;
        lhist[i] = 0;   // reuse as local cursor
    }
    __syncthreads();

#pragma unroll
    for (int k = 0; k < ITEMS; ++k) {
        if (myD[k] >= 0) {
            int b = myD[k] >> BIN_SHIFT;
            int off = lbase[b] + atomicAdd(&lhist[b], 1);
            if (off < BIN_CAP)
                bucket[(size_t)b * BIN_CAP + off] =
                    (unsigned)myS[k] | ((unsigned)(myD[k] & (BIN_NODES - 1)) << 17);
        }
    }
}

// k_agg: one block per bin, ATOMIC-FREE aggregation.
// Phase 1: LDS counting-sort of the bin's edges by node (int atomics only;
//          histogram == per-node degree, free).
// Phase 2: each node owned by a 2-lane pair; sequential register-accumulated
//          bf16 gathers (16B per lane), no atomics.
// Phase 3: fused mean + 16->128 projection + relu, coalesced float4 out.
__global__ __launch_bounds__(256) void k_agg(
    const int* __restrict__ binCount, const unsigned int* __restrict__ bucket,
    const unsigned short* __restrict__ pbf, const float* __restrict__ Wf,
    const float* __restrict__ bfv, float* __restrict__ out, int n_nodes)
{
    __shared__ unsigned sorted[BIN_CAP];        // 20 KB: src ids sorted by node
    __shared__ int hist[BIN_NODES];             // per-node degree
    __shared__ int basex[BIN_NODES];            // exclusive prefix
    __shared__ int cur[BIN_NODES];
    __shared__ int scanb[BIN_NODES];
    __shared__ float sWf[TT * DD];              // 8 KB
    __shared__ float sbf[DD];
    __shared__ float smsum[BIN_NODES][TT];      // 8 KB

    int tid = threadIdx.x;
    for (int i = tid; i < TT * DD; i += 256) sWf[i] = Wf[i];
    if (tid < DD) sbf[tid] = bfv[tid];
    if (tid < BIN_NODES) hist[tid] = 0;
    __syncthreads();

    int b = blockIdx.x;
    int cnt = binCount[b];
    if (cnt > BIN_CAP) cnt = BIN_CAP;
    const unsigned* bb = bucket + (size_t)b * BIN_CAP;

    // --- Phase 1a: histogram (coalesced global reads, int LDS atomics)
    for (int i = tid; i < cnt; i += 256)
        atomicAdd(&hist[(bb[i] >> 17) & (BIN_NODES - 1)], 1);
    __syncthreads();

    // --- Phase 1b: exclusive scan of hist[0..127] (Hillis-Steele)
    if (tid < BIN_NODES) scanb[tid] = hist[tid];
    __syncthreads();
    for (int off = 1; off < BIN_NODES; off <<= 1) {
        int v = 0;
        if (tid < BIN_NODES && tid >= off) v = scanb[tid - off];
        __syncthreads();
        if (tid < BIN_NODES) scanb[tid] += v;
        __syncthreads();
    }
    if (tid < BIN_NODES) {
        int excl = scanb[tid] - hist[tid];
        basex[tid] = excl;
        cur[tid] = excl;
    }
    __syncthreads();

    // --- Phase 1c: scatter into node-sorted LDS list
    for (int i = tid; i < cnt; i += 256) {
        unsigned e = bb[i];
        int d = (e >> 17) & (BIN_NODES - 1);
        int pos = atomicAdd(&cur[d], 1);
        sorted[pos] = e & 0x1FFFF;
    }
    __syncthreads();

    // --- Phase 2: register accumulation, 2 lanes per node (h = 16B half-row)
    {
        int nl = tid >> 1;
        int h = tid & 1;
        int beg = basex[nl];
        int dg = hist[nl];
        const uint4* prow4 = (const uint4*)pbf;   // node s: prow4[2s+h]
        float a0 = 0.f, a1 = 0.f, a2 = 0.f, a3 = 0.f;
        float a4 = 0.f, a5 = 0.f, a6 = 0.f, a7 = 0.f;
        for (int i = 0; i < dg; ++i) {
            unsigned s = sorted[beg + i];
            uint4 v = prow4[2 * (size_t)s + h];
            a0 += bfbits2f(v.x & 0xFFFF); a1 += bfbits2f(v.x >> 16);
            a2 += bfbits2f(v.y & 0xFFFF); a3 += bfbits2f(v.y >> 16);
            a4 += bfbits2f(v.z & 0xFFFF); a5 += bfbits2f(v.z >> 16);
            a6 += bfbits2f(v.w & 0xFFFF); a7 += bfbits2f(v.w >> 16);
        }
        float* row = &smsum[nl][h * 8];
        *(float4*)(row)     = make_float4(a0, a1, a2, a3);
        *(float4*)(row + 4) = make_float4(a4, a5, a6, a7);
    }
    __syncthreads();

    // --- Phase 3: mean + projection + relu (32 lanes per node)
    int node0 = b << BIN_SHIFT;
    int j0 = (tid & 31) * 4;
    for (int nl = tid >> 5; nl < BIN_NODES; nl += 8) {
        int n = node0 + nl;
        if (n >= n_nodes) continue;
        float invd = 1.0f / fmaxf((float)hist[nl], 1.0f);
        float4 acc = *(const float4*)(&sbf[j0]);
#pragma unroll
        for (int t = 0; t < TT; ++t) {
            float nd = smsum[nl][t] * invd;
            float4 w = *(const float4*)(&sWf[t * DD + j0]);
            acc.x = fmaf(nd, w.x, acc.x);
            acc.y = fmaf(nd, w.y, acc.y);
            acc.z = fmaf(nd, w.z, acc.z);
            acc.w = fmaf(nd, w.w, acc.w);
        }
        acc.x = fmaxf(acc.x, 0.f); acc.y = fmaxf(acc.y, 0.f);
        acc.z = fmaxf(acc.z, 0.f); acc.w = fmaxf(acc.w, 0.f);
        *(float4*)(&out[(size_t)n * DD + j0]) = acc;
    }
}

extern "C" void kernel_launch(void* const* d_in, const int* in_sizes, int n_in,
                              void* d_out, int out_size, void* d_ws, size_t ws_size,
                              hipStream_t stream) {
    const float* r   = (const float*)d_in[0];
    const int*   src = (const int*)d_in[1];
    const int*   dst = (const int*)d_in[2];
    const float* W1  = (const float*)d_in[3];
    const float* b1  = (const float*)d_in[4];
    const float* Wp  = (const float*)d_in[5];
    const float* bp  = (const float*)d_in[6];
    const float* Wf  = (const float*)d_in[7];
    const float* bf  = (const float*)d_in[8];
    float* out = (float*)d_out;

    int n_nodes = in_sizes[0] / TT;
    int n_edges = in_sizes[1];
    int nbins = (n_nodes + BIN_NODES - 1) >> BIN_SHIFT;

    auto al = [](size_t x) { return (x + 255) & ~(size_t)255; };
    size_t pB  = al((size_t)n_nodes * TT * 2);
    size_t bkB = al((size_t)nbins * BIN_CAP * 4);

    char* ws = (char*)d_ws;
    size_t off = 0;
    unsigned short* pbf = (unsigned short*)(ws + off); off += pB;
    unsigned int* bucket = (unsigned int*)(ws + off);  off += bkB;
    int* binCount = (int*)(ws + off);

    hipMemsetAsync(binCount, 0, (size_t)nbins * 4, stream);

    int blocksA = (n_nodes + 255) / 256;
    k_node_mlp<<<blocksA, 256, 0, stream>>>(r, W1, b1, Wp, bp, pbf, n_nodes);

    int blocksB = (n_edges + 256 * ITEMS - 1) / (256 * ITEMS);
    k_bin<<<blocksB, 256, 0, stream>>>(src, dst, binCount, bucket, n_edges, nbins);

    k_agg<<<nbins, 256, 0, stream>>>(binCount, bucket, pbf, Wf, bf, out, n_nodes);
}